// Round 7
// baseline (250.305 us; speedup 1.0000x reference)
//
#include <hip/hip_runtime.h>
#include <hip/hip_bf16.h>
#include <math.h>

// Problem constants
#define Bn   2
#define Nn   2048
#define Kn   48
#define Cn   128
#define G2   16     // nodes per block in the tail kernel
#define NP   4      // node-pairs per persistent block in kernel 1

typedef short bf16x8 __attribute__((ext_vector_type(8)));
typedef float f32x4  __attribute__((ext_vector_type(4)));

#if __has_builtin(__builtin_amdgcn_cvt_pk_bf16_f32)
#define HAS_PK 1
#endif

__device__ __forceinline__ short f2bf(float f) {
  union { float f; unsigned u; } v; v.f = f;
  unsigned r = v.u + 0x7fffu + ((v.u >> 16) & 1u);
  return (short)(r >> 16);
}

__device__ __forceinline__ unsigned pk2(float a, float b) {
#ifdef HAS_PK
  auto p = __builtin_amdgcn_cvt_pk_bf16_f32(a, b);
  return __builtin_bit_cast(unsigned, p);
#else
  return (unsigned)(unsigned short)f2bf(a) | ((unsigned)(unsigned short)f2bf(b) << 16);
#endif
}

// tanh-GELU with exp2-folded constants; |err| vs erf-gelu ~3e-4.
__device__ __forceinline__ float gelu_f(float x) {
  float z = x * (-2.3021991f - 0.10294200f * x * x);
  float e = __builtin_amdgcn_exp2f(z);
  return x * __builtin_amdgcn_rcpf(1.0f + e);
}

// ---------------------------------------------------------------------------
// Pack weights into bf16 MFMA B-fragment tiles (512 shorts each; lane l holds
// 8 bf16 = W[kt*32 + (l>>4)*8 + j][nt*16 + (l&15)]).
// ws (shorts): W1i [0,16384) | W1e [16384,49152) | W2 [49152,65536)
//              W3 [65536,81920) | Wu [81920,98304)
// ---------------------------------------------------------------------------
__global__ void pack_weights(const float* __restrict__ W1,
                             const float* __restrict__ W2,
                             const float* __restrict__ W3,
                             const float* __restrict__ Wu,
                             short* __restrict__ ws) {
  int tid = blockIdx.x * blockDim.x + threadIdx.x;
  if (tid >= 192 * 64) return;
  int lane = tid & 63;
  int tile = tid >> 6;
  const float* W; short* dst;
  if (tile < 32)       { W = W1;         dst = ws; }
  else if (tile < 96)  { W = W1 + 16384; dst = ws + 16384; tile -= 32; }
  else if (tile < 128) { W = W2;         dst = ws + 49152; tile -= 96; }
  else if (tile < 160) { W = W3;         dst = ws + 65536; tile -= 128; }
  else                 { W = Wu;         dst = ws + 81920; tile -= 160; }
  int kt = tile >> 3, nt = tile & 7;
  int n  = nt * 16 + (lane & 15);
  int k0 = kt * 32 + (lane >> 4) * 8;
  union { short s[8]; bf16x8 v; } u8;
#pragma unroll
  for (int j = 0; j < 8; j++) u8.s[j] = f2bf(W[(k0 + j) * 128 + n]);
  *reinterpret_cast<bf16x8*>(dst + (tile << 9) + lane * 8) = u8.v;
}

// ---------------------------------------------------------------------------
// Kernel 1 (Round 7): PERSISTENT blocks, NP=4 node-pairs per block, cross-pair
// software pipeline. Grid 512 x 512thr (8 waves; wave w owns cols [16w,16w+16)).
// Rationale: r2/r4/r5/r6 pinned k1 at ~65us across occupancy 37-72% and three
// scheduling variants -> the stall is the per-block serial phase chain
// (idx->gather->stage->6 barrier-drains) re-paid 2048x from cold. Here each
// block pays it once, then pipelines: ALL long-latency loads for pair i+1
// (edge ea/eb, gather na/nb, meta idx/nhb) are issued 1-2 phases ahead and fly
// across GEMM1b+GEMM2+barriers of pair i (~3-4k cy >> 900cy HBM latency).
// Barriers/pair 6 -> 4. LDS 51KB, bounds (512,4): 2 blk/CU (occupancy proven
// non-lever), VGPR cap 128 >> peak live ~105 so prefetches stay in registers.
// ---------------------------------------------------------------------------
__global__ __launch_bounds__(512, 4)
void node_update_kernel(const float* __restrict__ node_h,
                        const float* __restrict__ edge_h,
                        const int*   __restrict__ edge_index,
                        const short* __restrict__ wpack,
                        const float* __restrict__ b1,
                        const float* __restrict__ b2,
                        float* __restrict__ hs_out) {
  // LDS (bytes), 50944 total:
  //  [0,24576)      Xs 96x128 bf16 swz: node_j half; H1s overlays after GEMM1a
  //  [24576,49152)  Es 96x128 bf16 swz: edge half
  //  [49152,50176)  nhb2[2][256] bf16 (double-buffered node_i pair)
  //  [50176,50944)  idx2[2][96] int  (double-buffered neighbor indices)
  __shared__ __align__(16) char smem[50944];
  short* Xs   = (short*)smem;
  short* H1s  = (short*)smem;            // overlay of Xs
  short* Es   = (short*)(smem + 24576);
  short* nhb2 = (short*)(smem + 49152);
  int*   idx2 = (int*)  (smem + 50176);

  const int tid  = threadIdx.x;
  const int pair0 = blockIdx.x * NP;     // first pair of this block
  const int lane = tid & 63;
  const int wave = tid >> 6;             // 0..7
  const int lr   = lane & 15;
  const int lq   = lane >> 4;
  const int gw   = tid & 15;             // 16B granule within row
  const int gr   = tid >> 4;             // 0..31

  const short* W1i = wpack;
  const short* W1e = wpack + 16384;
  const short* W2p = wpack + 49152;

  // ---- hoisted invariants: W1i fragments (reused all NP pairs) + biases ----
  bf16x8 w1i[4];
#pragma unroll
  for (int kt = 0; kt < 4; kt++)
    w1i[kt] = *reinterpret_cast<const bf16x8*>(W1i + ((kt * 8 + wave) << 9) + lane * 8);
  const int colw = wave * 16 + lr;
  const float b1v = b1[colw];
  const float b2v = b2[colw];

  // ---- prologue: issue edge(pair0) loads (dense addresses, no deps) ----
  float4 ea[3], eb[3];
  {
    const int n0 = pair0 * 2;
#pragma unroll
    for (int k = 0; k < 3; k++) {
      int r = gr + k * 32;
      const float* src = edge_h + ((size_t)n0 * Kn + r) * Cn + gw * 8;
      ea[k] = *reinterpret_cast<const float4*>(src);
      eb[k] = *reinterpret_cast<const float4*>(src + 4);
    }
  }
  // meta(pair0) -> slot 0
  if (tid < 256) {
    nhb2[tid] = f2bf(node_h[(size_t)(pair0 * 2) * Cn + tid]);
  } else if (tid < 352) {
    idx2[tid - 256] = edge_index[(pair0 * 2) * Kn + (tid - 256)];
  }
  __syncthreads();
  // gather node_j(pair0) using idx2[0]
  float4 na[3], nb[3];
  {
    const int n0 = pair0 * 2;
    const int bb = n0 >> 11;
#pragma unroll
    for (int k = 0; k < 3; k++) {
      int r = gr + k * 32;
      const float* src = node_h + ((size_t)(bb * Nn) + idx2[r]) * Cn + gw * 8;
      na[k] = *reinterpret_cast<const float4*>(src);
      nb[k] = *reinterpret_cast<const float4*>(src + 4);
    }
  }

#pragma unroll
  for (int i = 0; i < NP; i++) {
    const int n0  = (pair0 + i) * 2;
    const int cur = i & 1;
    const int nxt = cur ^ 1;

    // ---- step A: meta(i+1) -> slot nxt; convert+write node_j(i) -> Xs;
    //      accY(i) from nhb2[cur] (hides the meta-load latency) ----
    if (i + 1 < NP) {
      if (tid < 256) {
        nhb2[nxt * 256 + tid] = f2bf(node_h[(size_t)(n0 + 2) * Cn + tid]);
      } else if (tid < 352) {
        idx2[nxt * 96 + (tid - 256)] = edge_index[(n0 + 2) * Kn + (tid - 256)];
      }
    }
    f32x4 accY[2] = {};
#pragma unroll
    for (int kt = 0; kt < 4; kt++) {
      bf16x8 avA = {}, avB = {};
      if (lr == 0) {
        avA = *reinterpret_cast<const bf16x8*>(&nhb2[cur * 256 + kt * 32 + lq * 8]);
        avB = *reinterpret_cast<const bf16x8*>(&nhb2[cur * 256 + 128 + kt * 32 + lq * 8]);
      }
      accY[0] = __builtin_amdgcn_mfma_f32_16x16x32_bf16(avA, w1i[kt], accY[0], 0, 0, 0);
      accY[1] = __builtin_amdgcn_mfma_f32_16x16x32_bf16(avB, w1i[kt], accY[1], 0, 0, 0);
    }
    const float yiA = __shfl(accY[0][0], lr) + b1v;
    const float yiB = __shfl(accY[1][0], lr) + b1v;
#pragma unroll
    for (int k = 0; k < 3; k++) {
      int r = gr + k * 32;
      uint4 p;
      p.x = pk2(na[k].x, na[k].y); p.y = pk2(na[k].z, na[k].w);
      p.z = pk2(nb[k].x, nb[k].y); p.w = pk2(nb[k].z, nb[k].w);
      *reinterpret_cast<uint4*>(&Xs[r * 128 + ((gw ^ (r & 7)) << 3)]) = p;
    }
    __syncthreads();   // B1: Xs staged; meta(i+1) visible

    // ---- step B: GEMM1a on Xs (node half); then write Es from edge regs ----
    f32x4 acc[6] = {};
#pragma unroll
    for (int kt = 0; kt < 4; kt++) {
      bf16x8 bf = *reinterpret_cast<const bf16x8*>(W1e + ((kt * 8 + wave) << 9) + lane * 8);
      int sw = (((kt * 4 + lq) ^ (lr & 7)) << 3);
#pragma unroll
      for (int m = 0; m < 6; m++) {
        bf16x8 a = *reinterpret_cast<const bf16x8*>(&Xs[(m * 16 + lr) * 128 + sw]);
        acc[m] = __builtin_amdgcn_mfma_f32_16x16x32_bf16(a, bf, acc[m], 0, 0, 0);
      }
    }
#pragma unroll
    for (int k = 0; k < 3; k++) {
      int r = gr + k * 32;
      uint4 p;
      p.x = pk2(ea[k].x, ea[k].y); p.y = pk2(ea[k].z, ea[k].w);
      p.z = pk2(eb[k].x, eb[k].y); p.w = pk2(eb[k].z, eb[k].w);
      *reinterpret_cast<uint4*>(&Es[r * 128 + ((gw ^ (r & 7)) << 3)]) = p;
    }
    __syncthreads();   // B2: Es has edge(i)

    // ---- step C: issue edge(i+1) + gather(i+1) (idx2[nxt] visible since B1);
    //      then GEMM1b on Es and epilogue -> H1s ----
    if (i + 1 < NP) {
      const int n2 = n0 + 2;
      const int bb2 = n2 >> 11;
#pragma unroll
      for (int k = 0; k < 3; k++) {
        int r = gr + k * 32;
        const float* esrc = edge_h + ((size_t)n2 * Kn + r) * Cn + gw * 8;
        ea[k] = *reinterpret_cast<const float4*>(esrc);
        eb[k] = *reinterpret_cast<const float4*>(esrc + 4);
      }
#pragma unroll
      for (int k = 0; k < 3; k++) {
        int r = gr + k * 32;
        const float* nsrc = node_h + ((size_t)(bb2 * Nn) + idx2[nxt * 96 + r]) * Cn + gw * 8;
        na[k] = *reinterpret_cast<const float4*>(nsrc);
        nb[k] = *reinterpret_cast<const float4*>(nsrc + 4);
      }
      __builtin_amdgcn_sched_barrier(0);   // pin: prefetches issued HERE
    }
#pragma unroll
    for (int kt = 0; kt < 4; kt++) {
      bf16x8 bf = *reinterpret_cast<const bf16x8*>(W1e + (((kt + 4) * 8 + wave) << 9) + lane * 8);
      int sw = (((kt * 4 + lq) ^ (lr & 7)) << 3);
#pragma unroll
      for (int m = 0; m < 6; m++) {
        bf16x8 a = *reinterpret_cast<const bf16x8*>(&Es[(m * 16 + lr) * 128 + sw]);
        acc[m] = __builtin_amdgcn_mfma_f32_16x16x32_bf16(a, bf, acc[m], 0, 0, 0);
      }
    }
    // epilogue: +yi, gelu, bf16 -> H1s (overlay Xs; all Xs reads ended at B2)
    {
      int g = colw >> 3, cl = colw & 7;
#pragma unroll
      for (int mt = 0; mt < 6; mt++) {
        float yi = (mt < 3) ? yiA : yiB;
        int r0 = mt * 16 + lq * 4;
        float g0 = gelu_f(acc[mt][0] + yi);
        float g1 = gelu_f(acc[mt][1] + yi);
        float g2 = gelu_f(acc[mt][2] + yi);
        float g3 = gelu_f(acc[mt][3] + yi);
        unsigned p01 = pk2(g0, g1), p23 = pk2(g2, g3);
        H1s[(r0 + 0) * 128 + ((g ^ ((r0 + 0) & 7)) << 3) + cl] = (short)(p01 & 0xffff);
        H1s[(r0 + 1) * 128 + ((g ^ ((r0 + 1) & 7)) << 3) + cl] = (short)(p01 >> 16);
        H1s[(r0 + 2) * 128 + ((g ^ ((r0 + 2) & 7)) << 3) + cl] = (short)(p23 & 0xffff);
        H1s[(r0 + 3) * 128 + ((g ^ ((r0 + 3) & 7)) << 3) + cl] = (short)(p23 >> 16);
      }
    }
    __syncthreads();   // B3: H1s visible

    // ---- step D: GEMM2 on H1s, fused gelu + column-sum; write hs ----
    f32x4 acc2[6] = {};
#pragma unroll
    for (int kt = 0; kt < 4; kt++) {
      bf16x8 bf = *reinterpret_cast<const bf16x8*>(W2p + ((kt * 8 + wave) << 9) + lane * 8);
      int sw = (((kt * 4 + lq) ^ (lr & 7)) << 3);
#pragma unroll
      for (int m = 0; m < 6; m++) {
        bf16x8 a = *reinterpret_cast<const bf16x8*>(&H1s[(m * 16 + lr) * 128 + sw]);
        acc2[m] = __builtin_amdgcn_mfma_f32_16x16x32_bf16(a, bf, acc2[m], 0, 0, 0);
      }
    }
    {
      float sA = 0.f, sB = 0.f;
#pragma unroll
      for (int mt = 0; mt < 3; mt++)
#pragma unroll
        for (int r = 0; r < 4; r++) {
          sA += gelu_f(acc2[mt][r] + b2v);
          sB += gelu_f(acc2[mt + 3][r] + b2v);
        }
      sA += __shfl_xor(sA, 16);
      sA += __shfl_xor(sA, 32);
      sB += __shfl_xor(sB, 16);
      sB += __shfl_xor(sB, 32);
      if (lq == 0) {
        hs_out[(size_t)n0 * Cn + colw]       = sA;
        hs_out[(size_t)(n0 + 1) * Cn + colw] = sB;
      }
    }
    __syncthreads();   // B4: H1s reads done before next iter's Xs writes
  }
}

// ---------------------------------------------------------------------------
// Kernel 2 (tail, batched): 16 nodes per block.
// msg = (hs @ W3 + 48*b3)/30 ; x = nh + msg ; u = LN(x) ;
// y = nh + u@Wu + bu ; out = LN(y).  Matvecs are dense M=16 MFMA GEMMs.
// Reads hs from the out buffer, overwrites the same rows at the end.
// ---------------------------------------------------------------------------
__global__ __launch_bounds__(256, 4)
void tail_kernel(const float* __restrict__ node_h,
                 const short* __restrict__ wpack,
                 const float* __restrict__ b3,
                 const float* __restrict__ bu,
                 const float* __restrict__ ln_g,
                 const float* __restrict__ ln_b,
                 float* __restrict__ out) {
  // LDS: hsB 16x128 bf16 swz [0,4096) | nhr 16x128 f32 [4096,12288)
  //      xs 16x132 f32 [12288,20736) | usB 16x128 bf16 swz [20736,24832)
  __shared__ __align__(16) char sm2[24832];
  short* hsB = (short*)sm2;
  float* nhr = (float*)(sm2 + 4096);
  float* xs  = (float*)(sm2 + 12288);
  short* usB = (short*)(sm2 + 20736);

  const int tid  = threadIdx.x;
  const int lane = tid & 63;
  const int wave = tid >> 6;
  const int lr   = lane & 15;
  const int lq   = lane >> 4;
  const int n0   = blockIdx.x * G2;

  const short* W3p = wpack + 65536;
  const short* Wup = wpack + 81920;

  // ---- stage node_h (f32) and hs (bf16, swizzled) ----
  {
    int row = tid >> 4, seg = tid & 15;
    const float* p = node_h + (size_t)(n0 + row) * Cn + seg * 8;
    float4 a0 = *reinterpret_cast<const float4*>(p);
    float4 a1 = *reinterpret_cast<const float4*>(p + 4);
    *reinterpret_cast<float4*>(&nhr[row * 128 + seg * 8])     = a0;
    *reinterpret_cast<float4*>(&nhr[row * 128 + seg * 8 + 4]) = a1;
    const float* q = out + (size_t)(n0 + row) * Cn + seg * 8;  // hs scratch
    float4 c0 = *reinterpret_cast<const float4*>(q);
    float4 c1 = *reinterpret_cast<const float4*>(q + 4);
    uint4 pk;
    pk.x = pk2(c0.x, c0.y); pk.y = pk2(c0.z, c0.w);
    pk.z = pk2(c1.x, c1.y); pk.w = pk2(c1.z, c1.w);
    *reinterpret_cast<uint4*>(&hsB[row * 128 + ((seg ^ (row & 7)) << 3)]) = pk;
  }
  __syncthreads();

  // ---- msg GEMM (M=16): hs @ W3 ; x = nh + (.+48*b3)/30 -> xs ----
  f32x4 am[2] = {};
#pragma unroll
  for (int kt = 0; kt < 4; kt++) {
    bf16x8 av = *reinterpret_cast<const bf16x8*>(&hsB[lr * 128 + (((kt * 4 + lq) ^ (lr & 7)) << 3)]);
    bf16x8 bv0 = *reinterpret_cast<const bf16x8*>(W3p + ((kt * 8 + wave * 2 + 0) << 9) + lane * 8);
    bf16x8 bv1 = *reinterpret_cast<const bf16x8*>(W3p + ((kt * 8 + wave * 2 + 1) << 9) + lane * 8);
    am[0] = __builtin_amdgcn_mfma_f32_16x16x32_bf16(av, bv0, am[0], 0, 0, 0);
    am[1] = __builtin_amdgcn_mfma_f32_16x16x32_bf16(av, bv1, am[1], 0, 0, 0);
  }
#pragma unroll
  for (int j = 0; j < 2; j++) {
    int col = (wave * 2 + j) * 16 + lr;
    float bb = 48.0f * b3[col];
#pragma unroll
    for (int r = 0; r < 4; r++) {
      int row = lq * 4 + r;
      xs[row * 132 + col] = nhr[row * 128 + col] + (am[j][r] + bb) * (1.0f / 30.0f);
    }
  }
  __syncthreads();

  // ---- LN1 -> usB (bf16 swz). Wave handles 4 rows; lane owns cols lane,lane+64.
  const float lg1 = ln_g[lane],      lb1v = ln_b[lane];
  const float lg2 = ln_g[lane + 64], lb2v = ln_b[lane + 64];
#pragma unroll
  for (int s = 0; s < 4; s++) {
    int row = wave * 4 + s;
    float v1 = xs[row * 132 + lane];
    float v2 = xs[row * 132 + lane + 64];
    float s1 = v1 + v2, s2 = v1 * v1 + v2 * v2;
#pragma unroll
    for (int off = 32; off >= 1; off >>= 1) {
      s1 += __shfl_xor(s1, off);
      s2 += __shfl_xor(s2, off);
    }
    float mu = s1 * (1.f / 128.f);
    float var = s2 * (1.f / 128.f) - mu * mu;
    float rstd = rsqrtf(var + 1e-5f);
    unsigned u12 = pk2((v1 - mu) * rstd * lg1 + lb1v,
                       (v2 - mu) * rstd * lg2 + lb2v);
    int sw = (row & 7);
    usB[row * 128 + (((lane >> 3) ^ sw) << 3) + (lane & 7)]       = (short)(u12 & 0xffff);
    usB[row * 128 + ((((lane >> 3) + 8) ^ sw) << 3) + (lane & 7)] = (short)(u12 >> 16);
  }
  __syncthreads();

  // ---- upd GEMM (M=16): u @ Wu ; y = nh + . + bu -> xs ----
  f32x4 au[2] = {};
#pragma unroll
  for (int kt = 0; kt < 4; kt++) {
    bf16x8 av = *reinterpret_cast<const bf16x8*>(&usB[lr * 128 + (((kt * 4 + lq) ^ (lr & 7)) << 3)]);
    bf16x8 bv0 = *reinterpret_cast<const bf16x8*>(Wup + ((kt * 8 + wave * 2 + 0) << 9) + lane * 8);
    bf16x8 bv1 = *reinterpret_cast<const bf16x8*>(Wup + ((kt * 8 + wave * 2 + 1) << 9) + lane * 8);
    au[0] = __builtin_amdgcn_mfma_f32_16x16x32_bf16(av, bv0, au[0], 0, 0, 0);
    au[1] = __builtin_amdgcn_mfma_f32_16x16x32_bf16(av, bv1, au[1], 0, 0, 0);
  }
  __syncthreads();   // xs LN1 reads done before overwrite
#pragma unroll
  for (int j = 0; j < 2; j++) {
    int col = (wave * 2 + j) * 16 + lr;
    float bb = bu[col];
#pragma unroll
    for (int r = 0; r < 4; r++) {
      int row = lq * 4 + r;
      xs[row * 132 + col] = nhr[row * 128 + col] + au[j][r] + bb;
    }
  }
  __syncthreads();

  // ---- LN2 -> out ----
#pragma unroll
  for (int s = 0; s < 4; s++) {
    int row = wave * 4 + s;
    float v1 = xs[row * 132 + lane];
    float v2 = xs[row * 132 + lane + 64];
    float s1 = v1 + v2, s2 = v1 * v1 + v2 * v2;
#pragma unroll
    for (int off = 32; off >= 1; off >>= 1) {
      s1 += __shfl_xor(s1, off);
      s2 += __shfl_xor(s2, off);
    }
    float mu = s1 * (1.f / 128.f);
    float var = s2 * (1.f / 128.f) - mu * mu;
    float rstd = rsqrtf(var + 1e-5f);
    out[(size_t)(n0 + row) * Cn + lane]      = (v1 - mu) * rstd * lg1 + lb1v;
    out[(size_t)(n0 + row) * Cn + lane + 64] = (v2 - mu) * rstd * lg2 + lb2v;
  }
}

extern "C" void kernel_launch(void* const* d_in, const int* in_sizes, int n_in,
                              void* d_out, int out_size, void* d_ws, size_t ws_size,
                              hipStream_t stream) {
  const float* node_h     = (const float*)d_in[0];
  const float* edge_h     = (const float*)d_in[1];
  const int*   edge_index = (const int*)  d_in[2];
  const float* W1 = (const float*)d_in[3];
  const float* b1 = (const float*)d_in[4];
  const float* W2 = (const float*)d_in[5];
  const float* b2 = (const float*)d_in[6];
  const float* W3 = (const float*)d_in[7];
  const float* b3 = (const float*)d_in[8];
  const float* Wu = (const float*)d_in[9];
  const float* bu = (const float*)d_in[10];
  const float* ln_g = (const float*)d_in[11];
  const float* ln_b = (const float*)d_in[12];
  float* out   = (float*)d_out;
  short* wpack = (short*)d_ws;   // 192 KiB

  pack_weights<<<48, 256, 0, stream>>>(W1, W2, W3, Wu, wpack);
  node_update_kernel<<<(Bn * Nn) / (2 * NP), 512, 0, stream>>>(
      node_h, edge_h, edge_index, wpack, b1, b2, out);
  tail_kernel<<<(Bn * Nn) / G2, 256, 0, stream>>>(
      node_h, wpack, b3, bu, ln_g, ln_b, out);
}

// Round 8
// 194.014 us; speedup vs baseline: 1.2901x; 1.2901x over previous
//
#include <hip/hip_runtime.h>
#include <hip/hip_bf16.h>
#include <math.h>

// Problem constants
#define Bn   2
#define Nn   2048
#define Kn   48
#define Cn   128
#define G2   16     // nodes per block in the tail kernel

typedef short bf16x8 __attribute__((ext_vector_type(8)));
typedef float f32x4  __attribute__((ext_vector_type(4)));

#if __has_builtin(__builtin_amdgcn_cvt_pk_bf16_f32)
#define HAS_PK 1
#endif

__device__ __forceinline__ short f2bf(float f) {
  union { float f; unsigned u; } v; v.f = f;
  unsigned r = v.u + 0x7fffu + ((v.u >> 16) & 1u);
  return (short)(r >> 16);
}

__device__ __forceinline__ unsigned pk2(float a, float b) {
#ifdef HAS_PK
  auto p = __builtin_amdgcn_cvt_pk_bf16_f32(a, b);
  return __builtin_bit_cast(unsigned, p);
#else
  return (unsigned)(unsigned short)f2bf(a) | ((unsigned)(unsigned short)f2bf(b) << 16);
#endif
}

// tanh-GELU with exp2-folded constants; |err| vs erf-gelu ~3e-4.
__device__ __forceinline__ float gelu_f(float x) {
  float z = x * (-2.3021991f - 0.10294200f * x * x);
  float e = __builtin_amdgcn_exp2f(z);
  return x * __builtin_amdgcn_rcpf(1.0f + e);
}

// LDS-visibility barrier WITHOUT the vmcnt(0) drain __syncthreads carries:
// drain only lgkmcnt (our ds_writes), raw s_barrier, sched fences so the
// compiler can neither sink LDS stores past it nor hoist LDS reads above it.
// Global loads in flight (gather/edge prefetch) stay outstanding across it.
#define LBAR()                                              \
  do {                                                      \
    __builtin_amdgcn_sched_barrier(0);                      \
    asm volatile("s_waitcnt lgkmcnt(0)" ::: "memory");      \
    __builtin_amdgcn_s_barrier();                           \
    __builtin_amdgcn_sched_barrier(0);                      \
  } while (0)

// ---------------------------------------------------------------------------
// Pack weights into bf16 MFMA B-fragment tiles (512 shorts each; lane l holds
// 8 bf16 = W[kt*32 + (l>>4)*8 + j][nt*16 + (l&15)]).
// ws (shorts): W1i [0,16384) | W1e [16384,49152) | W2 [49152,65536)
//              W3 [65536,81920) | Wu [81920,98304)
// ---------------------------------------------------------------------------
__global__ void pack_weights(const float* __restrict__ W1,
                             const float* __restrict__ W2,
                             const float* __restrict__ W3,
                             const float* __restrict__ Wu,
                             short* __restrict__ ws) {
  int tid = blockIdx.x * blockDim.x + threadIdx.x;
  if (tid >= 192 * 64) return;
  int lane = tid & 63;
  int tile = tid >> 6;
  const float* W; short* dst;
  if (tile < 32)       { W = W1;         dst = ws; }
  else if (tile < 96)  { W = W1 + 16384; dst = ws + 16384; tile -= 32; }
  else if (tile < 128) { W = W2;         dst = ws + 49152; tile -= 96; }
  else if (tile < 160) { W = W3;         dst = ws + 65536; tile -= 128; }
  else                 { W = Wu;         dst = ws + 81920; tile -= 160; }
  int kt = tile >> 3, nt = tile & 7;
  int n  = nt * 16 + (lane & 15);
  int k0 = kt * 32 + (lane >> 4) * 8;
  union { short s[8]; bf16x8 v; } u8;
#pragma unroll
  for (int j = 0; j < 8; j++) u8.s[j] = f2bf(W[(k0 + j) * 128 + n]);
  *reinterpret_cast<bf16x8*>(dst + (tile << 9) + lane * 8) = u8.v;
}

// ---------------------------------------------------------------------------
// Kernel 1 (Round 8): TWO nodes per block, 512 thr = 8 waves; wave w owns
// output cols [16w,16w+16). M = 96 rows. K-split GEMM1 with SEPARATE Es
// buffer and NO-vmcnt-drain barriers (LBAR): the documented __syncthreads
// "s_waitcnt vmcnt(0)" drain was force-landing every in-flight prefetch at
// every barrier (5x/pair) -- the T3/T4 lever never applied here. New order:
//   issue {W frags, idx->regs, nhb} -> LBAR
//   issue gather (covered by accY+convert slack)
//   issue edge   (crosses the Xs LBAR un-drained, lands under GEMM1a)
//   accY -> convert gather -> Xs -> LBAR -> GEMM1a -> convert edge -> Es
//   -> LBAR -> GEMM1b -> epilogue -> H1s(overlay Xs) -> LBAR -> GEMM2.
// 4 barriers/pair (was 5), idx LDS round-trip removed. LDS 48.5KB: 3 blk/CU.
// bounds (512,4): VGPR cap 128 >= peak live ~106 (no spill; WRITE_SIZE is
// the tell). VGPR_Count 90-126 expected if prefetches are truly held.
// ---------------------------------------------------------------------------
__global__ __launch_bounds__(512, 4)
void node_update_kernel(const float* __restrict__ node_h,
                        const float* __restrict__ edge_h,
                        const int*   __restrict__ edge_index,
                        const short* __restrict__ wpack,
                        const float* __restrict__ b1,
                        const float* __restrict__ b2,
                        float* __restrict__ hs_out) {
  // LDS (bytes), 49664 total:
  //  [0,24576)      Xs 96x128 bf16 swz (node_j); H1s overlays after GEMM1a
  //  [24576,49152)  Es 96x128 bf16 swz (edge)
  //  [49152,49664)  nhb: node_i bf16 x256 (2 nodes)
  __shared__ __align__(16) char smem[49664];
  short* Xs  = (short*)smem;
  short* H1s = (short*)smem;             // overlay of Xs
  short* Es  = (short*)(smem + 24576);
  short* nhb = (short*)(smem + 49152);

  const int tid  = threadIdx.x;
  const int n0   = blockIdx.x * 2;     // first node of the pair
  const int bb   = n0 >> 11;           // batch (pair never straddles: 2048 even)
  const int lane = tid & 63;
  const int wave = tid >> 6;           // 0..7
  const int lr   = lane & 15;
  const int lq   = lane >> 4;
  const int gw   = tid & 15;           // 16B granule within row
  const int gr   = tid >> 4;           // 0..31

  const short* W1i = wpack;
  const short* W1e = wpack + 16384;
  const short* W2p = wpack + 49152;

  // ---- P0: hoist W1i + GEMM1a W frags, idx -> registers, stage nhb ----
  bf16x8 w1i[4], w1a[4];
#pragma unroll
  for (int kt = 0; kt < 4; kt++)
    w1i[kt] = *reinterpret_cast<const bf16x8*>(W1i + ((kt * 8 + wave) << 9) + lane * 8);
#pragma unroll
  for (int kt = 0; kt < 4; kt++)
    w1a[kt] = *reinterpret_cast<const bf16x8*>(W1e + ((kt * 8 + wave) << 9) + lane * 8);
  const int colw = wave * 16 + lr;
  const float b1v = b1[colw];
  const float b2v = b2[colw];
  int idxr[3];
#pragma unroll
  for (int k = 0; k < 3; k++)
    idxr[k] = edge_index[n0 * Kn + gr + k * 32];
  if (tid < 256) nhb[tid] = f2bf(node_h[(size_t)n0 * Cn + tid]);
  LBAR();   // B1: nhb visible; W/idx loads still in flight is fine

  // ---- P2: issue gather (idx regs have landed by now) ----
  float4 na[3], nb[3];
#pragma unroll
  for (int k = 0; k < 3; k++) {
    const float* src = node_h + ((size_t)(bb * Nn) + idxr[k]) * Cn + gw * 8;
    na[k] = *reinterpret_cast<const float4*>(src);
    nb[k] = *reinterpret_cast<const float4*>(src + 4);
  }
  __builtin_amdgcn_sched_barrier(0);   // pin: gather issued HERE

  // ---- P3: issue edge (retires after gather; consumed after GEMM1a) ----
  float4 ea[3], eb[3];
#pragma unroll
  for (int k = 0; k < 3; k++) {
    int r = gr + k * 32;
    const float* src = edge_h + ((size_t)n0 * Kn + r) * Cn + gw * 8;
    ea[k] = *reinterpret_cast<const float4*>(src);
    eb[k] = *reinterpret_cast<const float4*>(src + 4);
  }
  __builtin_amdgcn_sched_barrier(0);   // pin: edge issued HERE

  // ---- P4: accY row-vector MFMAs (cover gather latency) ----
  f32x4 accY[2] = {};
#pragma unroll
  for (int kt = 0; kt < 4; kt++) {
    bf16x8 avA = {}, avB = {};
    if (lr == 0) {
      avA = *reinterpret_cast<const bf16x8*>(&nhb[kt * 32 + lq * 8]);
      avB = *reinterpret_cast<const bf16x8*>(&nhb[128 + kt * 32 + lq * 8]);
    }
    accY[0] = __builtin_amdgcn_mfma_f32_16x16x32_bf16(avA, w1i[kt], accY[0], 0, 0, 0);
    accY[1] = __builtin_amdgcn_mfma_f32_16x16x32_bf16(avB, w1i[kt], accY[1], 0, 0, 0);
  }
  const float yiA = __shfl(accY[0][0], lr) + b1v;
  const float yiB = __shfl(accY[1][0], lr) + b1v;

  // ---- P5: convert gather -> Xs (waits gather only; edge stays in flight) ----
#pragma unroll
  for (int k = 0; k < 3; k++) {
    int r = gr + k * 32;
    uint4 p;
    p.x = pk2(na[k].x, na[k].y); p.y = pk2(na[k].z, na[k].w);
    p.z = pk2(nb[k].x, nb[k].y); p.w = pk2(nb[k].z, nb[k].w);
    *reinterpret_cast<uint4*>(&Xs[r * 128 + ((gw ^ (r & 7)) << 3)]) = p;
  }
  LBAR();   // B2: Xs visible; EDGE LOADS CROSS UN-DRAINED

  // ---- P6: GEMM1a (Xs node_j @ W1[128:256]); edge lands underneath ----
  f32x4 acc[6] = {};
#pragma unroll
  for (int kt = 0; kt < 4; kt++) {
    int sw = (((kt * 4 + lq) ^ (lr & 7)) << 3);
#pragma unroll
    for (int m = 0; m < 6; m++) {
      bf16x8 a = *reinterpret_cast<const bf16x8*>(&Xs[(m * 16 + lr) * 128 + sw]);
      acc[m] = __builtin_amdgcn_mfma_f32_16x16x32_bf16(a, w1a[kt], acc[m], 0, 0, 0);
    }
  }

  // ---- P7: convert edge -> Es (separate buffer; no pre-overwrite barrier) ----
#pragma unroll
  for (int k = 0; k < 3; k++) {
    int r = gr + k * 32;
    uint4 p;
    p.x = pk2(ea[k].x, ea[k].y); p.y = pk2(ea[k].z, ea[k].w);
    p.z = pk2(eb[k].x, eb[k].y); p.w = pk2(eb[k].z, eb[k].w);
    *reinterpret_cast<uint4*>(&Es[r * 128 + ((gw ^ (r & 7)) << 3)]) = p;
  }
  LBAR();   // B3: Es visible; also guarantees all Xs reads (P6) are done

  // ---- P8: GEMM1b (Es edge @ W1[256:384]); W frags in-loop (L2-hot) ----
#pragma unroll
  for (int kt = 0; kt < 4; kt++) {
    bf16x8 bf = *reinterpret_cast<const bf16x8*>(W1e + (((kt + 4) * 8 + wave) << 9) + lane * 8);
    int sw = (((kt * 4 + lq) ^ (lr & 7)) << 3);
#pragma unroll
    for (int m = 0; m < 6; m++) {
      bf16x8 a = *reinterpret_cast<const bf16x8*>(&Es[(m * 16 + lr) * 128 + sw]);
      acc[m] = __builtin_amdgcn_mfma_f32_16x16x32_bf16(a, bf, acc[m], 0, 0, 0);
    }
  }

  // ---- P9: epilogue +yi +b1, gelu, bf16 -> H1s (overlay Xs; safe post-B3) ----
  {
    int g = colw >> 3, cl = colw & 7;
#pragma unroll
    for (int mt = 0; mt < 6; mt++) {
      float yi = (mt < 3) ? yiA : yiB;
      int r0 = mt * 16 + lq * 4;
      float g0 = gelu_f(acc[mt][0] + yi);
      float g1 = gelu_f(acc[mt][1] + yi);
      float g2 = gelu_f(acc[mt][2] + yi);
      float g3 = gelu_f(acc[mt][3] + yi);
      unsigned p01 = pk2(g0, g1), p23 = pk2(g2, g3);
      H1s[(r0 + 0) * 128 + ((g ^ ((r0 + 0) & 7)) << 3) + cl] = (short)(p01 & 0xffff);
      H1s[(r0 + 1) * 128 + ((g ^ ((r0 + 1) & 7)) << 3) + cl] = (short)(p01 >> 16);
      H1s[(r0 + 2) * 128 + ((g ^ ((r0 + 2) & 7)) << 3) + cl] = (short)(p23 & 0xffff);
      H1s[(r0 + 3) * 128 + ((g ^ ((r0 + 3) & 7)) << 3) + cl] = (short)(p23 >> 16);
    }
  }
  LBAR();   // B4: H1s visible

  // ---- P10: GEMM2 (H1s @ W2), fused gelu + column-sum; write hs f32 ----
  f32x4 acc2[6] = {};
#pragma unroll
  for (int kt = 0; kt < 4; kt++) {
    bf16x8 bf = *reinterpret_cast<const bf16x8*>(W2p + ((kt * 8 + wave) << 9) + lane * 8);
    int sw = (((kt * 4 + lq) ^ (lr & 7)) << 3);
#pragma unroll
    for (int m = 0; m < 6; m++) {
      bf16x8 a = *reinterpret_cast<const bf16x8*>(&H1s[(m * 16 + lr) * 128 + sw]);
      acc2[m] = __builtin_amdgcn_mfma_f32_16x16x32_bf16(a, bf, acc2[m], 0, 0, 0);
    }
  }
  {
    float sA = 0.f, sB = 0.f;
#pragma unroll
    for (int mt = 0; mt < 3; mt++)
#pragma unroll
      for (int r = 0; r < 4; r++) {
        sA += gelu_f(acc2[mt][r] + b2v);
        sB += gelu_f(acc2[mt + 3][r] + b2v);
      }
    sA += __shfl_xor(sA, 16);
    sA += __shfl_xor(sA, 32);
    sB += __shfl_xor(sB, 16);
    sB += __shfl_xor(sB, 32);
    if (lq == 0) {
      hs_out[(size_t)n0 * Cn + colw]       = sA;
      hs_out[(size_t)(n0 + 1) * Cn + colw] = sB;
    }
  }
}

// ---------------------------------------------------------------------------
// Kernel 2 (tail, batched): 16 nodes per block.
// msg = (hs @ W3 + 48*b3)/30 ; x = nh + msg ; u = LN(x) ;
// y = nh + u@Wu + bu ; out = LN(y).  Matvecs are dense M=16 MFMA GEMMs.
// Reads hs from the out buffer, overwrites the same rows at the end.
// ---------------------------------------------------------------------------
__global__ __launch_bounds__(256, 4)
void tail_kernel(const float* __restrict__ node_h,
                 const short* __restrict__ wpack,
                 const float* __restrict__ b3,
                 const float* __restrict__ bu,
                 const float* __restrict__ ln_g,
                 const float* __restrict__ ln_b,
                 float* __restrict__ out) {
  // LDS: hsB 16x128 bf16 swz [0,4096) | nhr 16x128 f32 [4096,12288)
  //      xs 16x132 f32 [12288,20736) | usB 16x128 bf16 swz [20736,24832)
  __shared__ __align__(16) char sm2[24832];
  short* hsB = (short*)sm2;
  float* nhr = (float*)(sm2 + 4096);
  float* xs  = (float*)(sm2 + 12288);
  short* usB = (short*)(sm2 + 20736);

  const int tid  = threadIdx.x;
  const int lane = tid & 63;
  const int wave = tid >> 6;
  const int lr   = lane & 15;
  const int lq   = lane >> 4;
  const int n0   = blockIdx.x * G2;

  const short* W3p = wpack + 65536;
  const short* Wup = wpack + 81920;

  // ---- stage node_h (f32) and hs (bf16, swizzled) ----
  {
    int row = tid >> 4, seg = tid & 15;
    const float* p = node_h + (size_t)(n0 + row) * Cn + seg * 8;
    float4 a0 = *reinterpret_cast<const float4*>(p);
    float4 a1 = *reinterpret_cast<const float4*>(p + 4);
    *reinterpret_cast<float4*>(&nhr[row * 128 + seg * 8])     = a0;
    *reinterpret_cast<float4*>(&nhr[row * 128 + seg * 8 + 4]) = a1;
    const float* q = out + (size_t)(n0 + row) * Cn + seg * 8;  // hs scratch
    float4 c0 = *reinterpret_cast<const float4*>(q);
    float4 c1 = *reinterpret_cast<const float4*>(q + 4);
    uint4 pk;
    pk.x = pk2(c0.x, c0.y); pk.y = pk2(c0.z, c0.w);
    pk.z = pk2(c1.x, c1.y); pk.w = pk2(c1.z, c1.w);
    *reinterpret_cast<uint4*>(&hsB[row * 128 + ((seg ^ (row & 7)) << 3)]) = pk;
  }
  __syncthreads();

  // ---- msg GEMM (M=16): hs @ W3 ; x = nh + (.+48*b3)/30 -> xs ----
  f32x4 am[2] = {};
#pragma unroll
  for (int kt = 0; kt < 4; kt++) {
    bf16x8 av = *reinterpret_cast<const bf16x8*>(&hsB[lr * 128 + (((kt * 4 + lq) ^ (lr & 7)) << 3)]);
    bf16x8 bv0 = *reinterpret_cast<const bf16x8*>(W3p + ((kt * 8 + wave * 2 + 0) << 9) + lane * 8);
    bf16x8 bv1 = *reinterpret_cast<const bf16x8*>(W3p + ((kt * 8 + wave * 2 + 1) << 9) + lane * 8);
    am[0] = __builtin_amdgcn_mfma_f32_16x16x32_bf16(av, bv0, am[0], 0, 0, 0);
    am[1] = __builtin_amdgcn_mfma_f32_16x16x32_bf16(av, bv1, am[1], 0, 0, 0);
  }
#pragma unroll
  for (int j = 0; j < 2; j++) {
    int col = (wave * 2 + j) * 16 + lr;
    float bb = 48.0f * b3[col];
#pragma unroll
    for (int r = 0; r < 4; r++) {
      int row = lq * 4 + r;
      xs[row * 132 + col] = nhr[row * 128 + col] + (am[j][r] + bb) * (1.0f / 30.0f);
    }
  }
  __syncthreads();

  // ---- LN1 -> usB (bf16 swz). Wave handles 4 rows; lane owns cols lane,lane+64.
  const float lg1 = ln_g[lane],      lb1v = ln_b[lane];
  const float lg2 = ln_g[lane + 64], lb2v = ln_b[lane + 64];
#pragma unroll
  for (int s = 0; s < 4; s++) {
    int row = wave * 4 + s;
    float v1 = xs[row * 132 + lane];
    float v2 = xs[row * 132 + lane + 64];
    float s1 = v1 + v2, s2 = v1 * v1 + v2 * v2;
#pragma unroll
    for (int off = 32; off >= 1; off >>= 1) {
      s1 += __shfl_xor(s1, off);
      s2 += __shfl_xor(s2, off);
    }
    float mu = s1 * (1.f / 128.f);
    float var = s2 * (1.f / 128.f) - mu * mu;
    float rstd = rsqrtf(var + 1e-5f);
    unsigned u12 = pk2((v1 - mu) * rstd * lg1 + lb1v,
                       (v2 - mu) * rstd * lg2 + lb2v);
    int sw = (row & 7);
    usB[row * 128 + (((lane >> 3) ^ sw) << 3) + (lane & 7)]       = (short)(u12 & 0xffff);
    usB[row * 128 + ((((lane >> 3) + 8) ^ sw) << 3) + (lane & 7)] = (short)(u12 >> 16);
  }
  __syncthreads();

  // ---- upd GEMM (M=16): u @ Wu ; y = nh + . + bu -> xs ----
  f32x4 au[2] = {};
#pragma unroll
  for (int kt = 0; kt < 4; kt++) {
    bf16x8 av = *reinterpret_cast<const bf16x8*>(&usB[lr * 128 + (((kt * 4 + lq) ^ (lr & 7)) << 3)]);
    bf16x8 bv0 = *reinterpret_cast<const bf16x8*>(Wup + ((kt * 8 + wave * 2 + 0) << 9) + lane * 8);
    bf16x8 bv1 = *reinterpret_cast<const bf16x8*>(Wup + ((kt * 8 + wave * 2 + 1) << 9) + lane * 8);
    au[0] = __builtin_amdgcn_mfma_f32_16x16x32_bf16(av, bv0, au[0], 0, 0, 0);
    au[1] = __builtin_amdgcn_mfma_f32_16x16x32_bf16(av, bv1, au[1], 0, 0, 0);
  }
  __syncthreads();   // xs LN1 reads done before overwrite
#pragma unroll
  for (int j = 0; j < 2; j++) {
    int col = (wave * 2 + j) * 16 + lr;
    float bb = bu[col];
#pragma unroll
    for (int r = 0; r < 4; r++) {
      int row = lq * 4 + r;
      xs[row * 132 + col] = nhr[row * 128 + col] + au[j][r] + bb;
    }
  }
  __syncthreads();

  // ---- LN2 -> out ----
#pragma unroll
  for (int s = 0; s < 4; s++) {
    int row = wave * 4 + s;
    float v1 = xs[row * 132 + lane];
    float v2 = xs[row * 132 + lane + 64];
    float s1 = v1 + v2, s2 = v1 * v1 + v2 * v2;
#pragma unroll
    for (int off = 32; off >= 1; off >>= 1) {
      s1 += __shfl_xor(s1, off);
      s2 += __shfl_xor(s2, off);
    }
    float mu = s1 * (1.f / 128.f);
    float var = s2 * (1.f / 128.f) - mu * mu;
    float rstd = rsqrtf(var + 1e-5f);
    out[(size_t)(n0 + row) * Cn + lane]      = (v1 - mu) * rstd * lg1 + lb1v;
    out[(size_t)(n0 + row) * Cn + lane + 64] = (v2 - mu) * rstd * lg2 + lb2v;
  }
}

extern "C" void kernel_launch(void* const* d_in, const int* in_sizes, int n_in,
                              void* d_out, int out_size, void* d_ws, size_t ws_size,
                              hipStream_t stream) {
  const float* node_h     = (const float*)d_in[0];
  const float* edge_h     = (const float*)d_in[1];
  const int*   edge_index = (const int*)  d_in[2];
  const float* W1 = (const float*)d_in[3];
  const float* b1 = (const float*)d_in[4];
  const float* W2 = (const float*)d_in[5];
  const float* b2 = (const float*)d_in[6];
  const float* W3 = (const float*)d_in[7];
  const float* b3 = (const float*)d_in[8];
  const float* Wu = (const float*)d_in[9];
  const float* bu = (const float*)d_in[10];
  const float* ln_g = (const float*)d_in[11];
  const float* ln_b = (const float*)d_in[12];
  float* out   = (float*)d_out;
  short* wpack = (short*)d_ws;   // 192 KiB

  pack_weights<<<48, 256, 0, stream>>>(W1, W2, W3, Wu, wpack);
  node_update_kernel<<<(Bn * Nn) / 2, 512, 0, stream>>>(
      node_h, edge_h, edge_index, wpack, b1, b2, out);
  tail_kernel<<<(Bn * Nn) / G2, 256, 0, stream>>>(
      node_h, wpack, b3, bu, ln_g, ln_b, out);
}